// Round 1
// baseline (1794.496 us; speedup 1.0000x reference)
//
#include <hip/hip_runtime.h>
#include <math.h>

// GARNN: graph-attention GRU, B=16, N=512, U=64, SEQ=12, HORIZON=12, all f32.
// Structure: 2 kernels per cell (phaseB = ru-attention + h_c; phaseA = c-attention
// + state update (+proj) + next cell's h_ru/src/dst, fused since h_new is node-local).

#define NB 16
#define NN 512
#define NU 64
#define CAP 128   // neighbor-list capacity (Bin(511,0.1) max << 128)

__device__ __forceinline__ float rlane(float v, int l) {
  return __int_as_float(__builtin_amdgcn_readlane(__float_as_int(v), l));
}
__device__ __forceinline__ int rlane_i(int v, int l) {
  return __builtin_amdgcn_readlane(v, l);
}
__device__ __forceinline__ float wave_max(float v) {
  #pragma unroll
  for (int s = 1; s < 64; s <<= 1) v = fmaxf(v, __shfl_xor(v, s));
  return v;
}
__device__ __forceinline__ float wave_sum(float v) {
  #pragma unroll
  for (int s = 1; s < 64; s <<= 1) v += __shfl_xor(v, s);
  return v;
}
__device__ __forceinline__ float sigmoidf_(float x) {
  return 1.0f / (1.0f + expf(-x));
}

// Build per-row neighbor lists: mask[i][j] = adj[i][j] > 0.9 || i == j, ascending j.
__global__ __launch_bounds__(64) void k_adj(const float* __restrict__ adj,
                                            int* __restrict__ cnt,
                                            int* __restrict__ idx) {
  int i = blockIdx.x;
  int l = threadIdx.x;
  int base = 0;
  #pragma unroll
  for (int c = 0; c < 8; ++c) {
    int j = c * 64 + l;
    bool pred = (adj[i * NN + j] > 0.9f) || (j == i);
    unsigned long long m = __ballot(pred);
    int pos = base + __popcll(m & ((1ull << l) - 1ull));
    if (pred && pos < CAP) idx[i * CAP + pos] = j;
    base += __popcll(m);
  }
  if (l == 0) cnt[i] = base > CAP ? CAP : base;
}

// Phase B: ru-attention -> r,u ; write u; compute h_c = [x, r*h] @ W_c, src_c, dst_c.
// One wave per (b,i) node. g = 2*lane, 2*lane+1 covers 2U=128.
__global__ __launch_bounds__(256) void k_phaseB(
    const int* __restrict__ cnt, const int* __restrict__ idx,
    const float* __restrict__ h_ru, const float* __restrict__ src_ru,
    const float* __restrict__ dst_ru, const float* __restrict__ b_ru,
    const float* __restrict__ h, const float* __restrict__ x_ptr, int din,
    const float* __restrict__ W_c, const float* __restrict__ a_c,
    float* __restrict__ h_c, float* __restrict__ src_c,
    float* __restrict__ dst_c, float* __restrict__ u_buf) {
  __shared__ float sW[66 * NU];
  int tid = threadIdx.x;
  int nW = (din + NU) * NU;
  for (int k = tid; k < nW; k += 256) sW[k] = W_c[k];
  __syncthreads();

  int w = tid >> 6, lane = tid & 63;
  int gn = blockIdx.x * 4 + w;
  int b = gn >> 9, i = gn & 511;
  int base_bi = b * NN + i;

  int c_ = cnt[i];
  float si = src_ru[base_bi];
  int j0 = 0, j1 = 0;
  float e0 = -__builtin_inff(), e1 = -__builtin_inff();
  if (lane < c_) {
    j0 = idx[i * CAP + lane];
    float t = si + dst_ru[b * NN + j0];
    e0 = t >= 0.f ? t : 0.2f * t;
  }
  if (lane + 64 < c_) {
    j1 = idx[i * CAP + lane + 64];
    float t = si + dst_ru[b * NN + j1];
    e1 = t >= 0.f ? t : 0.2f * t;
  }
  float m = wave_max(fmaxf(e0, e1));
  float p0 = (lane < c_) ? expf(e0 - m) : 0.f;
  float p1 = (lane + 64 < c_) ? expf(e1 - m) : 0.f;
  float inv = 1.f / wave_sum(p0 + p1);
  p0 *= inv; p1 *= inv;

  // aggregation: ru[g] over neighbors, g = 2*lane, 2*lane+1
  float A0 = 0.f, A1 = 0.f;
  for (int jj = 0; jj < c_; ++jj) {
    int sl = jj & 63;
    float pv; int j;
    if (jj < 64) { pv = rlane(p0, sl); j = rlane_i(j0, sl); }
    else         { pv = rlane(p1, sl); j = rlane_i(j1, sl); }
    const float2 hr = *(const float2*)(h_ru + ((size_t)(b * NN + j)) * 128 + 2 * lane);
    A0 = fmaf(pv, hr.x, A0);
    A1 = fmaf(pv, hr.y, A1);
  }
  int g0 = 2 * lane;
  float ru0 = sigmoidf_(A0 + b_ru[g0]);
  float ru1 = sigmoidf_(A1 + b_ru[g0 + 1]);

  // lanes 0..31 hold r (g<64); lanes 32..63 hold u (g>=64)
  float rh0 = 0.f, rh1 = 0.f;
  if (lane < 32) {
    float2 hh = *(const float2*)(h + (size_t)base_bi * NU + g0);
    rh0 = ru0 * hh.x;
    rh1 = ru1 * hh.y;
  } else {
    *(float2*)(u_buf + (size_t)base_bi * NU + (g0 - 64)) = make_float2(ru0, ru1);
  }

  // h_c GEMV: gc = lane; xc = [x, r*h]
  float acc = 0.f;
  float x0 = x_ptr[(size_t)base_bi * din];
  acc = fmaf(x0, sW[lane], acc);
  if (din == 2) {
    float x1 = x_ptr[(size_t)base_bi * 2 + 1];
    acc = fmaf(x1, sW[NU + lane], acc);
  }
  const float* sWh = sW + din * NU;
  #pragma unroll
  for (int f = 0; f < NU; ++f) {
    float rv = (f & 1) ? rlane(rh1, f >> 1) : rlane(rh0, f >> 1);
    acc = fmaf(rv, sWh[f * NU + lane], acc);
  }
  h_c[(size_t)base_bi * NU + lane] = acc;
  float s0 = wave_sum(acc * a_c[lane]);
  float s1 = wave_sum(acc * a_c[NU + lane]);
  if (lane == 0) { src_c[base_bi] = s0; dst_c[base_bi] = s1; }
}

// Phase A: c-attention -> c; h_new = u*h + (1-u)*c (or h=0 init); optional proj to
// output+y_buf; optional next-cell h_ru = [x_next, h_new] @ W_ru + src/dst.
__global__ __launch_bounds__(256) void k_phaseA(
    const int* __restrict__ cnt, const int* __restrict__ idx,
    const float* __restrict__ h_c, const float* __restrict__ src_c,
    const float* __restrict__ dst_c, const float* __restrict__ b_c,
    const float* __restrict__ u_buf, float* __restrict__ h,
    const float* __restrict__ proj_W, const float* __restrict__ proj_b,
    float* __restrict__ out_slice, float* __restrict__ y_buf,
    int mode_update, int din_next, int xmode,
    const float* __restrict__ x_ptr,
    const float* __restrict__ W_ru, const float* __restrict__ a_ru,
    float* __restrict__ h_ru, float* __restrict__ src_ru,
    float* __restrict__ dst_ru) {
  __shared__ float sW[66 * 128];
  int tid = threadIdx.x;
  if (din_next > 0) {
    int nW = (din_next + NU) * 128;
    for (int k = tid; k < nW; k += 256) sW[k] = W_ru[k];
  }
  __syncthreads();

  int w = tid >> 6, lane = tid & 63;
  int gn = blockIdx.x * 4 + w;
  int b = gn >> 9, i = gn & 511;
  int base_bi = b * NN + i;

  float hn = 0.f;
  if (mode_update) {
    int c_ = cnt[i];
    float si = src_c[base_bi];
    int j0 = 0, j1 = 0;
    float e0 = -__builtin_inff(), e1 = -__builtin_inff();
    if (lane < c_) {
      j0 = idx[i * CAP + lane];
      float t = si + dst_c[b * NN + j0];
      e0 = t >= 0.f ? t : 0.2f * t;
    }
    if (lane + 64 < c_) {
      j1 = idx[i * CAP + lane + 64];
      float t = si + dst_c[b * NN + j1];
      e1 = t >= 0.f ? t : 0.2f * t;
    }
    float m = wave_max(fmaxf(e0, e1));
    float p0 = (lane < c_) ? expf(e0 - m) : 0.f;
    float p1 = (lane + 64 < c_) ? expf(e1 - m) : 0.f;
    float inv = 1.f / wave_sum(p0 + p1);
    p0 *= inv; p1 *= inv;

    float acc = 0.f;
    for (int jj = 0; jj < c_; ++jj) {
      int sl = jj & 63;
      float pv; int j;
      if (jj < 64) { pv = rlane(p0, sl); j = rlane_i(j0, sl); }
      else         { pv = rlane(p1, sl); j = rlane_i(j1, sl); }
      acc = fmaf(pv, h_c[((size_t)(b * NN + j)) * NU + lane], acc);
    }
    float cc = tanhf(acc + b_c[lane]);
    float u = u_buf[(size_t)base_bi * NU + lane];
    float ho = h[(size_t)base_bi * NU + lane];
    hn = u * ho + (1.f - u) * cc;
  }
  h[(size_t)base_bi * NU + lane] = hn;

  float y = 0.f;
  if (out_slice != nullptr) {
    float t = wave_sum(hn * proj_W[lane]);
    y = t + proj_b[0];  // all lanes (butterfly gives full result everywhere)
    if (lane == 0) { out_slice[base_bi] = y; y_buf[base_bi] = y; }
  }

  if (din_next > 0) {
    float x0 = 0.f, x1 = 0.f;
    if (xmode == 0) {
      x0 = x_ptr[(size_t)base_bi * din_next];
      if (din_next == 2) x1 = x_ptr[(size_t)base_bi * 2 + 1];
    } else if (xmode == 2) {
      x0 = y;
    } // xmode==1: zeros (decoder GO token)

    int g0 = 2 * lane;
    float a0 = x0 * sW[g0], a1 = x0 * sW[g0 + 1];
    if (din_next == 2) {
      a0 = fmaf(x1, sW[128 + g0], a0);
      a1 = fmaf(x1, sW[128 + g0 + 1], a1);
    }
    const float* sWh = sW + din_next * 128;
    #pragma unroll
    for (int f = 0; f < NU; ++f) {
      float hv = rlane(hn, f);
      const float2 wv = *(const float2*)(sWh + f * 128 + g0);
      a0 = fmaf(hv, wv.x, a0);
      a1 = fmaf(hv, wv.y, a1);
    }
    *(float2*)(h_ru + (size_t)base_bi * 128 + g0) = make_float2(a0, a1);
    float s0 = wave_sum(a0 * a_ru[g0] + a1 * a_ru[g0 + 1]);
    float s1 = wave_sum(a0 * a_ru[128 + g0] + a1 * a_ru[128 + g0 + 1]);
    if (lane == 0) { src_ru[base_bi] = s0; dst_ru[base_bi] = s1; }
  }
}

extern "C" void kernel_launch(void* const* d_in, const int* in_sizes, int n_in,
                              void* d_out, int out_size, void* d_ws, size_t ws_size,
                              hipStream_t stream) {
  (void)in_sizes; (void)n_in; (void)out_size; (void)ws_size;
  const float* inputs   = (const float*)d_in[0];
  const float* adj      = (const float*)d_in[1];
  const float* enc_W_ru = (const float*)d_in[2];
  const float* enc_a_ru = (const float*)d_in[3];
  const float* enc_b_ru = (const float*)d_in[4];
  const float* enc_W_c  = (const float*)d_in[5];
  const float* enc_a_c  = (const float*)d_in[6];
  const float* enc_b_c  = (const float*)d_in[7];
  const float* dec_W_ru = (const float*)d_in[8];
  const float* dec_a_ru = (const float*)d_in[9];
  const float* dec_b_ru = (const float*)d_in[10];
  const float* dec_W_c  = (const float*)d_in[11];
  const float* dec_a_c  = (const float*)d_in[12];
  const float* dec_b_c  = (const float*)d_in[13];
  const float* proj_W   = (const float*)d_in[14];
  const float* proj_b   = (const float*)d_in[15];
  float* out = (float*)d_out;

  char* ws = (char*)d_ws;
  int*   cnt    = (int*)ws;                    // 512*4        = 2048
  int*   idx    = (int*)(ws + 2048);           // 512*128*4    = 262144
  float* h      = (float*)(ws + 264192);       // 16*512*64*4  = 2097152
  float* h_ru   = (float*)(ws + 2361344);      // 16*512*128*4 = 4194304
  float* src_ru = (float*)(ws + 6555648);      // 32768
  float* dst_ru = (float*)(ws + 6588416);      // 32768
  float* h_c    = (float*)(ws + 6621184);      // 2097152
  float* src_c  = (float*)(ws + 8718336);      // 32768
  float* dst_c  = (float*)(ws + 8751104);      // 32768
  float* u_buf  = (float*)(ws + 8783872);      // 2097152
  float* y_buf  = (float*)(ws + 10881024);     // 32768 (end 10913792)

  hipMemsetAsync(y_buf, 0, NB * NN * sizeof(float), stream);
  k_adj<<<NN, 64, 0, stream>>>(adj, cnt, idx);

  const int GRID = (NB * NN) / 4;  // 4 waves/block, 1 node/wave

  // init: h = 0, compute h_ru(x_0) with encoder weights
  k_phaseA<<<GRID, 256, 0, stream>>>(cnt, idx, h_c, src_c, dst_c, enc_b_c, u_buf, h,
      proj_W, proj_b, nullptr, y_buf, /*upd*/0, /*din_next*/2, /*xmode*/0,
      inputs, enc_W_ru, enc_a_ru, h_ru, src_ru, dst_ru);

  for (int t = 0; t < 12; ++t) {
    k_phaseB<<<GRID, 256, 0, stream>>>(cnt, idx, h_ru, src_ru, dst_ru, enc_b_ru,
        h, inputs + (size_t)t * NB * NN * 2, 2, enc_W_c, enc_a_c,
        h_c, src_c, dst_c, u_buf);
    if (t < 11)
      k_phaseA<<<GRID, 256, 0, stream>>>(cnt, idx, h_c, src_c, dst_c, enc_b_c, u_buf, h,
          proj_W, proj_b, nullptr, y_buf, 1, 2, 0,
          inputs + (size_t)(t + 1) * NB * NN * 2, enc_W_ru, enc_a_ru,
          h_ru, src_ru, dst_ru);
    else  // last encoder cell: prepare decoder cell 0 (x = GO = zeros)
      k_phaseA<<<GRID, 256, 0, stream>>>(cnt, idx, h_c, src_c, dst_c, enc_b_c, u_buf, h,
          proj_W, proj_b, nullptr, y_buf, 1, 1, 1,
          nullptr, dec_W_ru, dec_a_ru, h_ru, src_ru, dst_ru);
  }

  for (int k = 0; k < 12; ++k) {
    k_phaseB<<<GRID, 256, 0, stream>>>(cnt, idx, h_ru, src_ru, dst_ru, dec_b_ru,
        h, y_buf, 1, dec_W_c, dec_a_c, h_c, src_c, dst_c, u_buf);
    k_phaseA<<<GRID, 256, 0, stream>>>(cnt, idx, h_c, src_c, dst_c, dec_b_c, u_buf, h,
        proj_W, proj_b, out + (size_t)k * NB * NN, y_buf, 1,
        (k < 11) ? 1 : 0, /*xmode: local y*/2,
        nullptr, dec_W_ru, dec_a_ru, h_ru, src_ru, dst_ru);
  }
}

// Round 2
// 952.724 us; speedup vs baseline: 1.8835x; 1.8835x over previous
//
#include <hip/hip_runtime.h>
#include <math.h>

// GARNN: graph-attention GRU, B=16, N=512, U=64, SEQ=12, HORIZON=12, all f32.
// 2 kernels per cell (phaseB = ru-attention + h_c; phaseA = c-attention + update
// + next cell's h_ru/src/dst). R1: 512-thread blocks (8 nodes/blk share one LDS
// weight copy) + 16-deep register-prefetched neighbor gather (MLP, not serial).

#define NB 16
#define NN 512
#define NU 64
#define CAP 128   // neighbor-list capacity (Bin(511,0.1) max << 128)
#define WPB 8     // waves (=nodes) per block

__device__ __forceinline__ float rlane(float v, int l) {
  return __int_as_float(__builtin_amdgcn_readlane(__float_as_int(v), l));
}
__device__ __forceinline__ int rlane_i(int v, int l) {
  return __builtin_amdgcn_readlane(v, l);
}
__device__ __forceinline__ float wave_max(float v) {
  #pragma unroll
  for (int s = 1; s < 64; s <<= 1) v = fmaxf(v, __shfl_xor(v, s));
  return v;
}
__device__ __forceinline__ float wave_sum(float v) {
  #pragma unroll
  for (int s = 1; s < 64; s <<= 1) v += __shfl_xor(v, s);
  return v;
}
__device__ __forceinline__ float sigmoidf_(float x) {
  return 1.0f / (1.0f + expf(-x));
}

// Build per-row neighbor lists: mask[i][j] = adj[i][j] > 0.9 || i == j, ascending j.
// Pad tail [cnt, CAP) with j=i so the gather loop can run unpredicated (p=0 there).
__global__ __launch_bounds__(64) void k_adj(const float* __restrict__ adj,
                                            int* __restrict__ cnt,
                                            int* __restrict__ idx) {
  int i = blockIdx.x;
  int l = threadIdx.x;
  int base = 0;
  #pragma unroll
  for (int c = 0; c < 8; ++c) {
    int j = c * 64 + l;
    bool pred = (adj[i * NN + j] > 0.9f) || (j == i);
    unsigned long long m = __ballot(pred);
    int pos = base + __popcll(m & ((1ull << l) - 1ull));
    if (pred && pos < CAP) idx[i * CAP + pos] = j;
    base += __popcll(m);
  }
  int total = base > CAP ? CAP : base;
  for (int p = total + l; p < CAP; p += 64) idx[i * CAP + p] = i;  // pad
  if (l == 0) cnt[i] = total;
}

// Phase B: ru-attention -> r,u ; write u; compute h_c = [x, r*h] @ W_c, src_c, dst_c.
// One wave per (b,i) node. g = 2*lane, 2*lane+1 covers 2U=128.
__global__ __launch_bounds__(512, 6) void k_phaseB(
    const int* __restrict__ cnt, const int* __restrict__ idx,
    const float* __restrict__ h_ru, const float* __restrict__ src_ru,
    const float* __restrict__ dst_ru, const float* __restrict__ b_ru,
    const float* __restrict__ h, const float* __restrict__ x_ptr, int din,
    const float* __restrict__ W_c, const float* __restrict__ a_c,
    float* __restrict__ h_c, float* __restrict__ src_c,
    float* __restrict__ dst_c, float* __restrict__ u_buf) {
  __shared__ float sW[66 * NU];
  int tid = threadIdx.x;
  int nW = (din + NU) * NU;
  for (int k = tid; k < nW; k += 512) sW[k] = W_c[k];
  __syncthreads();

  int w = tid >> 6, lane = tid & 63;
  int gn = blockIdx.x * WPB + w;
  int b = gn >> 9, i = gn & 511;
  int base_bi = b * NN + i;

  int c_ = cnt[i];
  float si = src_ru[base_bi];
  int j0 = idx[i * CAP + lane];
  int j1 = idx[i * CAP + lane + 64];
  float e0 = -__builtin_inff(), e1 = -__builtin_inff();
  if (lane < c_) {
    float t = si + dst_ru[b * NN + j0];
    e0 = t >= 0.f ? t : 0.2f * t;
  }
  if (lane + 64 < c_) {
    float t = si + dst_ru[b * NN + j1];
    e1 = t >= 0.f ? t : 0.2f * t;
  }
  float m = wave_max(fmaxf(e0, e1));
  float p0 = (lane < c_) ? expf(e0 - m) : 0.f;
  float p1 = (lane + 64 < c_) ? expf(e1 - m) : 0.f;
  float inv = 1.f / wave_sum(p0 + p1);
  p0 *= inv; p1 *= inv;

  // aggregation: ru[g] over neighbors, g = 2*lane, 2*lane+1.
  // 16-deep register prefetch: 16 independent loads in flight per group.
  float A0 = 0.f, A1 = 0.f;
  int cc = (c_ + 15) & ~15;
  for (int base = 0; base < cc; base += 16) {
    float2 hv[16];
    #pragma unroll
    for (int q = 0; q < 16; ++q) {
      int jj = base + q;
      int sl = jj & 63;
      int j = (jj < 64) ? rlane_i(j0, sl) : rlane_i(j1, sl);
      hv[q] = *(const float2*)(h_ru + ((size_t)(b * NN + j)) * 128 + 2 * lane);
    }
    #pragma unroll
    for (int q = 0; q < 16; ++q) {
      int jj = base + q;
      int sl = jj & 63;
      float pv = (jj < 64) ? rlane(p0, sl) : rlane(p1, sl);
      A0 = fmaf(pv, hv[q].x, A0);
      A1 = fmaf(pv, hv[q].y, A1);
    }
  }
  int g0 = 2 * lane;
  float ru0 = sigmoidf_(A0 + b_ru[g0]);
  float ru1 = sigmoidf_(A1 + b_ru[g0 + 1]);

  // lanes 0..31 hold r (g<64); lanes 32..63 hold u (g>=64)
  float rh0 = 0.f, rh1 = 0.f;
  if (lane < 32) {
    float2 hh = *(const float2*)(h + (size_t)base_bi * NU + g0);
    rh0 = ru0 * hh.x;
    rh1 = ru1 * hh.y;
  } else {
    *(float2*)(u_buf + (size_t)base_bi * NU + (g0 - 64)) = make_float2(ru0, ru1);
  }

  // h_c GEMV: gc = lane; xc = [x, r*h]
  float acc = 0.f;
  float x0 = x_ptr[(size_t)base_bi * din];
  acc = fmaf(x0, sW[lane], acc);
  if (din == 2) {
    float x1 = x_ptr[(size_t)base_bi * 2 + 1];
    acc = fmaf(x1, sW[NU + lane], acc);
  }
  const float* sWh = sW + din * NU;
  #pragma unroll
  for (int f = 0; f < NU; ++f) {
    float rv = (f & 1) ? rlane(rh1, f >> 1) : rlane(rh0, f >> 1);
    acc = fmaf(rv, sWh[f * NU + lane], acc);
  }
  h_c[(size_t)base_bi * NU + lane] = acc;
  float s0 = wave_sum(acc * a_c[lane]);
  float s1 = wave_sum(acc * a_c[NU + lane]);
  if (lane == 0) { src_c[base_bi] = s0; dst_c[base_bi] = s1; }
}

// Phase A: c-attention -> c; h_new = u*h + (1-u)*c (or h=0 init); optional proj to
// output+y_buf; optional next-cell h_ru = [x_next, h_new] @ W_ru + src/dst.
__global__ __launch_bounds__(512, 6) void k_phaseA(
    const int* __restrict__ cnt, const int* __restrict__ idx,
    const float* __restrict__ h_c, const float* __restrict__ src_c,
    const float* __restrict__ dst_c, const float* __restrict__ b_c,
    const float* __restrict__ u_buf, float* __restrict__ h,
    const float* __restrict__ proj_W, const float* __restrict__ proj_b,
    float* __restrict__ out_slice, float* __restrict__ y_buf,
    int mode_update, int din_next, int xmode,
    const float* __restrict__ x_ptr,
    const float* __restrict__ W_ru, const float* __restrict__ a_ru,
    float* __restrict__ h_ru, float* __restrict__ src_ru,
    float* __restrict__ dst_ru) {
  __shared__ float sW[66 * 128];
  int tid = threadIdx.x;
  if (din_next > 0) {
    int nW = (din_next + NU) * 128;
    for (int k = tid; k < nW; k += 512) sW[k] = W_ru[k];
  }
  __syncthreads();

  int w = tid >> 6, lane = tid & 63;
  int gn = blockIdx.x * WPB + w;
  int b = gn >> 9, i = gn & 511;
  int base_bi = b * NN + i;

  float hn = 0.f;
  if (mode_update) {
    int c_ = cnt[i];
    float si = src_c[base_bi];
    int j0 = idx[i * CAP + lane];
    int j1 = idx[i * CAP + lane + 64];
    float e0 = -__builtin_inff(), e1 = -__builtin_inff();
    if (lane < c_) {
      float t = si + dst_c[b * NN + j0];
      e0 = t >= 0.f ? t : 0.2f * t;
    }
    if (lane + 64 < c_) {
      float t = si + dst_c[b * NN + j1];
      e1 = t >= 0.f ? t : 0.2f * t;
    }
    float m = wave_max(fmaxf(e0, e1));
    float p0 = (lane < c_) ? expf(e0 - m) : 0.f;
    float p1 = (lane + 64 < c_) ? expf(e1 - m) : 0.f;
    float inv = 1.f / wave_sum(p0 + p1);
    p0 *= inv; p1 *= inv;

    float acc = 0.f;
    int cc = (c_ + 15) & ~15;
    for (int base = 0; base < cc; base += 16) {
      float hv[16];
      #pragma unroll
      for (int q = 0; q < 16; ++q) {
        int jj = base + q;
        int sl = jj & 63;
        int j = (jj < 64) ? rlane_i(j0, sl) : rlane_i(j1, sl);
        hv[q] = h_c[((size_t)(b * NN + j)) * NU + lane];
      }
      #pragma unroll
      for (int q = 0; q < 16; ++q) {
        int jj = base + q;
        int sl = jj & 63;
        float pv = (jj < 64) ? rlane(p0, sl) : rlane(p1, sl);
        acc = fmaf(pv, hv[q], acc);
      }
    }
    float cc_ = tanhf(acc + b_c[lane]);
    float u = u_buf[(size_t)base_bi * NU + lane];
    float ho = h[(size_t)base_bi * NU + lane];
    hn = u * ho + (1.f - u) * cc_;
  }
  h[(size_t)base_bi * NU + lane] = hn;

  float y = 0.f;
  if (out_slice != nullptr) {
    float t = wave_sum(hn * proj_W[lane]);
    y = t + proj_b[0];  // all lanes (butterfly gives full result everywhere)
    if (lane == 0) { out_slice[base_bi] = y; y_buf[base_bi] = y; }
  }

  if (din_next > 0) {
    float x0 = 0.f, x1 = 0.f;
    if (xmode == 0) {
      x0 = x_ptr[(size_t)base_bi * din_next];
      if (din_next == 2) x1 = x_ptr[(size_t)base_bi * 2 + 1];
    } else if (xmode == 2) {
      x0 = y;
    } // xmode==1: zeros (decoder GO token)

    int g0 = 2 * lane;
    float a0 = x0 * sW[g0], a1 = x0 * sW[g0 + 1];
    if (din_next == 2) {
      a0 = fmaf(x1, sW[128 + g0], a0);
      a1 = fmaf(x1, sW[128 + g0 + 1], a1);
    }
    const float* sWh = sW + din_next * 128;
    #pragma unroll
    for (int f = 0; f < NU; ++f) {
      float hv = rlane(hn, f);
      const float2 wv = *(const float2*)(sWh + f * 128 + g0);
      a0 = fmaf(hv, wv.x, a0);
      a1 = fmaf(hv, wv.y, a1);
    }
    *(float2*)(h_ru + (size_t)base_bi * 128 + g0) = make_float2(a0, a1);
    float s0 = wave_sum(a0 * a_ru[g0] + a1 * a_ru[g0 + 1]);
    float s1 = wave_sum(a0 * a_ru[128 + g0] + a1 * a_ru[128 + g0 + 1]);
    if (lane == 0) { src_ru[base_bi] = s0; dst_ru[base_bi] = s1; }
  }
}

extern "C" void kernel_launch(void* const* d_in, const int* in_sizes, int n_in,
                              void* d_out, int out_size, void* d_ws, size_t ws_size,
                              hipStream_t stream) {
  (void)in_sizes; (void)n_in; (void)out_size; (void)ws_size;
  const float* inputs   = (const float*)d_in[0];
  const float* adj      = (const float*)d_in[1];
  const float* enc_W_ru = (const float*)d_in[2];
  const float* enc_a_ru = (const float*)d_in[3];
  const float* enc_b_ru = (const float*)d_in[4];
  const float* enc_W_c  = (const float*)d_in[5];
  const float* enc_a_c  = (const float*)d_in[6];
  const float* enc_b_c  = (const float*)d_in[7];
  const float* dec_W_ru = (const float*)d_in[8];
  const float* dec_a_ru = (const float*)d_in[9];
  const float* dec_b_ru = (const float*)d_in[10];
  const float* dec_W_c  = (const float*)d_in[11];
  const float* dec_a_c  = (const float*)d_in[12];
  const float* dec_b_c  = (const float*)d_in[13];
  const float* proj_W   = (const float*)d_in[14];
  const float* proj_b   = (const float*)d_in[15];
  float* out = (float*)d_out;

  char* ws = (char*)d_ws;
  int*   cnt    = (int*)ws;                    // 512*4        = 2048
  int*   idx    = (int*)(ws + 2048);           // 512*128*4    = 262144
  float* h      = (float*)(ws + 264192);       // 16*512*64*4  = 2097152
  float* h_ru   = (float*)(ws + 2361344);      // 16*512*128*4 = 4194304
  float* src_ru = (float*)(ws + 6555648);      // 32768
  float* dst_ru = (float*)(ws + 6588416);      // 32768
  float* h_c    = (float*)(ws + 6621184);      // 2097152
  float* src_c  = (float*)(ws + 8718336);      // 32768
  float* dst_c  = (float*)(ws + 8751104);      // 32768
  float* u_buf  = (float*)(ws + 8783872);      // 2097152
  float* y_buf  = (float*)(ws + 10881024);     // 32768 (end 10913792)

  hipMemsetAsync(y_buf, 0, NB * NN * sizeof(float), stream);
  k_adj<<<NN, 64, 0, stream>>>(adj, cnt, idx);

  const int GRID = (NB * NN) / WPB;  // 8 waves/block, 1 node/wave

  // init: h = 0, compute h_ru(x_0) with encoder weights
  k_phaseA<<<GRID, 512, 0, stream>>>(cnt, idx, h_c, src_c, dst_c, enc_b_c, u_buf, h,
      proj_W, proj_b, nullptr, y_buf, /*upd*/0, /*din_next*/2, /*xmode*/0,
      inputs, enc_W_ru, enc_a_ru, h_ru, src_ru, dst_ru);

  for (int t = 0; t < 12; ++t) {
    k_phaseB<<<GRID, 512, 0, stream>>>(cnt, idx, h_ru, src_ru, dst_ru, enc_b_ru,
        h, inputs + (size_t)t * NB * NN * 2, 2, enc_W_c, enc_a_c,
        h_c, src_c, dst_c, u_buf);
    if (t < 11)
      k_phaseA<<<GRID, 512, 0, stream>>>(cnt, idx, h_c, src_c, dst_c, enc_b_c, u_buf, h,
          proj_W, proj_b, nullptr, y_buf, 1, 2, 0,
          inputs + (size_t)(t + 1) * NB * NN * 2, enc_W_ru, enc_a_ru,
          h_ru, src_ru, dst_ru);
    else  // last encoder cell: prepare decoder cell 0 (x = GO = zeros)
      k_phaseA<<<GRID, 512, 0, stream>>>(cnt, idx, h_c, src_c, dst_c, enc_b_c, u_buf, h,
          proj_W, proj_b, nullptr, y_buf, 1, 1, 1,
          nullptr, dec_W_ru, dec_a_ru, h_ru, src_ru, dst_ru);
  }

  for (int k = 0; k < 12; ++k) {
    k_phaseB<<<GRID, 512, 0, stream>>>(cnt, idx, h_ru, src_ru, dst_ru, dec_b_ru,
        h, y_buf, 1, dec_W_c, dec_a_c, h_c, src_c, dst_c, u_buf);
    k_phaseA<<<GRID, 512, 0, stream>>>(cnt, idx, h_c, src_c, dst_c, dec_b_c, u_buf, h,
        proj_W, proj_b, out + (size_t)k * NB * NN, y_buf, 1,
        (k < 11) ? 1 : 0, /*xmode: local y*/2,
        nullptr, dec_W_ru, dec_a_ru, h_ru, src_ru, dst_ru);
  }
}